// Round 4
// 4690.635 us; speedup vs baseline: 1.1140x; 1.1140x over previous
//
#include <hip/hip_runtime.h>

#define TT 500
#define NB_BATCH 64
#define HID 1024
#define NC 2048   // 2*HID (z-gate cols 0..1023, h-gate cols 1024..2047)

typedef __attribute__((ext_vector_type(8))) __bf16 bf16x8;
typedef __attribute__((ext_vector_type(8))) unsigned short us8;
typedef __attribute__((ext_vector_type(4))) unsigned short us4;
typedef __attribute__((ext_vector_type(4))) float f32x4;
typedef __attribute__((ext_vector_type(2))) unsigned long long u64x2;

__device__ __forceinline__ unsigned short f2bf(float f) {
  unsigned u = __builtin_bit_cast(unsigned, f);
  u += 0x7fffu + ((u >> 16) & 1u);
  return (unsigned short)(u >> 16);
}
__device__ __forceinline__ float bf2f(unsigned short h) {
  unsigned u = ((unsigned)h) << 16;
  return __builtin_bit_cast(float, u);
}
__device__ __forceinline__ bf16x8 ld_bf8(const unsigned short* p) {
  return __builtin_bit_cast(bf16x8, *(const us8*)p);
}

// ---------------------------------------------------------------------------
// Kernel 0: fp32 -> bf16 elementwise convert (8 elems/thread, exact grids).
// ---------------------------------------------------------------------------
__global__ __launch_bounds__(256) void conv_f32_bf16(
    const float* __restrict__ src, unsigned short* __restrict__ dst)
{
  int i = blockIdx.x * 256 + threadIdx.x;
  const float4* s = (const float4*)src + (size_t)i * 2;
  float4 a = s[0], b = s[1];
  us8 o;
  o[0] = f2bf(a.x); o[1] = f2bf(a.y); o[2] = f2bf(a.z); o[3] = f2bf(a.w);
  o[4] = f2bf(b.x); o[5] = f2bf(b.y); o[6] = f2bf(b.z); o[7] = f2bf(b.w);
  *((us8*)dst + i) = o;
}

// ---------------------------------------------------------------------------
// Kernel 1: fused input projection + BatchNorm.
// R6: X and W arrive pre-converted bf16 -> staging is pure us4 (8B) copies,
// no f2bf VALU in the k-loop. MFMA layout / BN epilogue unchanged from the
// passing R3 kernel (numerically bit-identical: same f2bf applied earlier).
// ---------------------------------------------------------------------------
#define XS_STR 40
#define WS_STR 40

__global__ __launch_bounds__(256) void proj_bn_kernel(
    const unsigned short* __restrict__ X, int K,
    const unsigned short* __restrict__ Wxz, const unsigned short* __restrict__ Wxh,
    const float* __restrict__ gz, const float* __restrict__ bz,
    const float* __restrict__ gh, const float* __restrict__ bh,
    unsigned short* __restrict__ A)
{
  __shared__ unsigned short Xs[64 * XS_STR];
  __shared__ unsigned short Ws[128 * WS_STR];

  const int t   = blockIdx.x >> 4;
  const int nt  = blockIdx.x & 15;
  const int tid = threadIdx.x;
  const int wave = tid >> 6;
  const int lane = tid & 63;
  const int lm = lane & 15;
  const int lq = lane >> 4;

  const unsigned short* Wsrc = (nt < 8) ? (Wxz + (size_t)(nt * 128) * K)
                                        : (Wxh + (size_t)((nt - 8) * 128) * K);
  const unsigned short* Xbase = X + (size_t)(t * 64) * K;

  f32x4 acc[4][2];
#pragma unroll
  for (int i = 0; i < 4; i++)
#pragma unroll
    for (int j = 0; j < 2; j++) acc[i][j] = (f32x4){0.f, 0.f, 0.f, 0.f};

  const int nkt = K >> 5;
  for (int kt = 0; kt < nkt; ++kt) {
    const int k0 = kt << 5;
#pragma unroll
    for (int it = 0; it < 2; ++it) {
      int idx = it * 256 + tid;
      int r = idx >> 3, c4 = idx & 7;
      *(us4*)&Xs[r * XS_STR + c4 * 4] =
          *(const us4*)(Xbase + (size_t)r * K + k0 + c4 * 4);
    }
#pragma unroll
    for (int it = 0; it < 4; ++it) {
      int idx = it * 256 + tid;
      int r = idx >> 3, c4 = idx & 7;
      *(us4*)&Ws[r * WS_STR + c4 * 4] =
          *(const us4*)(Wsrc + (size_t)r * K + k0 + c4 * 4);
    }
    __syncthreads();
    bf16x8 bfr0 = ld_bf8(&Ws[(wave * 32 + lm) * WS_STR + lq * 8]);
    bf16x8 bfr1 = ld_bf8(&Ws[(wave * 32 + 16 + lm) * WS_STR + lq * 8]);
#pragma unroll
    for (int rt = 0; rt < 4; ++rt) {
      bf16x8 afr = ld_bf8(&Xs[(rt * 16 + lm) * XS_STR + lq * 8]);
      acc[rt][0] = __builtin_amdgcn_mfma_f32_16x16x32_bf16(afr, bfr0, acc[rt][0], 0, 0, 0);
      acc[rt][1] = __builtin_amdgcn_mfma_f32_16x16x32_bf16(afr, bfr1, acc[rt][1], 0, 0, 0);
    }
    __syncthreads();
  }

  const float inv64 = 1.0f / 64.0f;
#pragma unroll
  for (int ct = 0; ct < 2; ++ct) {
    float s1 = 0.f, s2 = 0.f;
#pragma unroll
    for (int rt = 0; rt < 4; ++rt)
#pragma unroll
      for (int r = 0; r < 4; ++r) {
        float v = acc[rt][ct][r];
        s1 += v; s2 += v * v;
      }
    s1 += __shfl_xor(s1, 16, 64); s2 += __shfl_xor(s2, 16, 64);
    s1 += __shfl_xor(s1, 32, 64); s2 += __shfl_xor(s2, 32, 64);
    float mean = s1 * inv64;
    float var  = s2 * inv64 - mean * mean;
    int col = nt * 128 + wave * 32 + ct * 16 + lm;
    float g, be;
    if (col < 1024) { g = gz[col];        be = bz[col]; }
    else            { g = gh[col - 1024]; be = bh[col - 1024]; }
    float scale = g * rsqrtf(var + 1e-5f);
    float shift = be - mean * scale;
    unsigned short* Aout = A + (size_t)(t * 64) * NC + col;
#pragma unroll
    for (int rt = 0; rt < 4; ++rt)
#pragma unroll
      for (int r = 0; r < 4; ++r) {
        int b = rt * 16 + lq * 4 + r;
        Aout[(size_t)b * NC] = f2bf(acc[rt][ct][r] * scale + shift);
      }
  }
}

// ---------------------------------------------------------------------------
// Kernel 2: persistent scan — R3 protocol VERBATIM (proven passing).
// Only change vs R3: ys store format is selectable (ysfmt=0 -> packed bf16
// for layer 0, consumed by layer-1 proj; ysfmt=1 -> fp32 as before for the
// final output). The branch is wave-uniform, per-thread, off the critical
// path, and does not touch the flag/drain/poll protocol in any way.
// ---------------------------------------------------------------------------
__global__ __launch_bounds__(64) void scan_kernel(
    const unsigned short* __restrict__ A,   // [T][64][2048] bf16
    const float* __restrict__ Whz, const float* __restrict__ bhz,
    const float* __restrict__ Whh, const float* __restrict__ bhh,
    unsigned short* __restrict__ hbuf,      // [2][64][1024] bf16
    float* __restrict__ ys,                 // [T][64][1024] fp32 OR bf16
    unsigned* __restrict__ flags,           // 256 x 16 uints (64B padded)
    const int ysfmt)                        // 1=fp32, 0=packed bf16
{
  extern __shared__ unsigned short Wlds[];  // 2 * 16 * 1024 bf16 = 64 KB
  const int lane = threadIdx.x;
  const int fg = blockIdx.x & 63;
  const int bg = blockIdx.x >> 6;
  const int lm = lane & 15;
  const int lq = lane >> 4;
  const int jg = fg * 16 + lm;   // this lane's feature column

  // Stage both weight slices (fp32 -> bf16), rotated-chunk layout:
  // elem off = g*16384 + r*1024 + ((c + 5*r)&127)*8 + half*4
  for (int g = 0; g < 2; ++g) {
    const float* Wsrc = (g ? Whh : Whz) + (size_t)(fg * 16) * HID;
#pragma unroll 4
    for (int it = 0; it < 64; ++it) {
      int idx = it * 64 + lane;          // 0..4095
      int r = idx >> 8, c4 = idx & 255;  // row, float4 index
      float4 v = *(const float4*)(Wsrc + (size_t)r * HID + c4 * 4);
      int c = c4 >> 1, hh = c4 & 1;
      us4 o; o[0] = f2bf(v.x); o[1] = f2bf(v.y); o[2] = f2bf(v.z); o[3] = f2bf(v.w);
      *(us4*)&Wlds[g * 16384 + r * 1024 + (((c + 5 * r) & 127) << 3) + hh * 4] = o;
    }
  }
  const float bzv = bhz[jg];
  const float bhv = bhh[jg];
  __syncthreads();

  // prefetch az/ah for t=0 (lane owns rows b = bg*16 + lq*4 + r, col jg)
  unsigned short aznx[4], ahnx[4];
  {
    const unsigned short* p = A + (size_t)(bg * 16 + lq * 4) * NC + jg;
#pragma unroll
    for (int r = 0; r < 4; ++r) { aznx[r] = p[(size_t)r * NC]; ahnx[r] = p[(size_t)r * NC + 1024]; }
  }
  float h_own[4] = {0.f, 0.f, 0.f, 0.f};

  unsigned* myflag   = &flags[blockIdx.x * 16];
  unsigned* pollflag = &flags[(bg * 64 + lane) * 16];

  for (int t = 0; t < TT; ++t) {
    f32x4 accz = {0.f, 0.f, 0.f, 0.f}, acch = {0.f, 0.f, 0.f, 0.f};

    // current-step a's; issue prefetch of t+1 early (hidden under MFMA)
    unsigned short azc[4], ahc[4];
#pragma unroll
    for (int r = 0; r < 4; ++r) { azc[r] = aznx[r]; ahc[r] = ahnx[r]; }
    if (t + 1 < TT) {
      const unsigned short* p = A + ((size_t)(t + 1) * 64 + bg * 16 + lq * 4) * NC + jg;
#pragma unroll
      for (int r = 0; r < 4; ++r) { aznx[r] = p[(size_t)r * NC]; ahnx[r] = p[(size_t)r * NC + 1024]; }
    }

    if (t > 0) {
      // ---- poll group flags (relaxed, one flag per lane, no acquire) ----
      const unsigned tv = (unsigned)t;
      unsigned v = __hip_atomic_load(pollflag, __ATOMIC_RELAXED, __HIP_MEMORY_SCOPE_AGENT);
      while (__ballot(v < tv)) {
        __builtin_amdgcn_s_sleep(1);
        v = __hip_atomic_load(pollflag, __ATOMIC_RELAXED, __HIP_MEMORY_SCOPE_AGENT);
      }
      __atomic_signal_fence(__ATOMIC_SEQ_CST);

      // ---- load h row lm (all 64 x 8B relaxed-agent loads up front) ----
      const unsigned long long* hq = (const unsigned long long*)
          (hbuf + (size_t)(t & 1) * 65536 + (size_t)(bg * 16 + lm) * HID) + lq * 2;
      unsigned long long harr[64];
#pragma unroll
      for (int kt = 0; kt < 32; ++kt) {
        harr[2 * kt]     = __hip_atomic_load(hq + kt * 8,     __ATOMIC_RELAXED, __HIP_MEMORY_SCOPE_AGENT);
        harr[2 * kt + 1] = __hip_atomic_load(hq + kt * 8 + 1, __ATOMIC_RELAXED, __HIP_MEMORY_SCOPE_AGENT);
      }
#pragma unroll
      for (int kt = 0; kt < 32; ++kt) {
        u64x2 u; u[0] = harr[2 * kt]; u[1] = harr[2 * kt + 1];
        bf16x8 afr = __builtin_bit_cast(bf16x8, u);
        int c = ((kt * 4 + lq) + 5 * lm) & 127;
        bf16x8 bz8 = ld_bf8(&Wlds[lm * 1024 + c * 8]);
        bf16x8 bh8 = ld_bf8(&Wlds[16384 + lm * 1024 + c * 8]);
        accz = __builtin_amdgcn_mfma_f32_16x16x32_bf16(afr, bz8, accz, 0, 0, 0);
        acch = __builtin_amdgcn_mfma_f32_16x16x32_bf16(afr, bh8, acch, 0, 0, 0);
      }
    }

    // ---- elementwise update; store h (t+1 buffer) via relaxed 4B stores ----
    unsigned short* hb = hbuf + (size_t)((t + 1) & 1) * 65536;
    unsigned short mybf[4];
#pragma unroll
    for (int r = 0; r < 4; ++r) {
      float z  = 1.0f / (1.0f + __expf(-(bf2f(azc[r]) + accz[r] + bzv)));
      float ht = bf2f(ahc[r]) + acch[r] + bhv;
      ht = ht > 0.f ? ht : 0.f;
      float h2 = z * h_own[r] + (1.0f - z) * ht;
      h_own[r] = h2;
      mybf[r] = f2bf(h2);
    }
#pragma unroll
    for (int r = 0; r < 4; ++r) {
      int p = __shfl((int)mybf[r], lane ^ 1, 64);
      if (!(lane & 1)) {
        unsigned w = (unsigned)mybf[r] | ((unsigned)p << 16);
        int row = bg * 16 + lq * 4 + r;
        __hip_atomic_store((unsigned*)(hb + (size_t)row * HID + jg), w,
                           __ATOMIC_RELAXED, __HIP_MEMORY_SCOPE_AGENT);
      }
    }

    // ---- signal: drain stores to coherence point, then relaxed flag ----
    __atomic_signal_fence(__ATOMIC_SEQ_CST);
    __builtin_amdgcn_s_waitcnt(0);
    __atomic_signal_fence(__ATOMIC_SEQ_CST);
    if (lane == 0)
      __hip_atomic_store(myflag, (unsigned)(t + 1), __ATOMIC_RELAXED, __HIP_MEMORY_SCOPE_AGENT);

    // ---- ys store (off critical path, normal cached stores) ----
    if (ysfmt) {
      float* ysp = ys + ((size_t)t * 64 + bg * 16 + lq * 4) * HID + jg;
#pragma unroll
      for (int r = 0; r < 4; ++r) ysp[(size_t)r * HID] = h_own[r];
    } else {
      unsigned short* yb = (unsigned short*)ys +
          ((size_t)t * 64 + bg * 16 + lq * 4) * HID + jg;
#pragma unroll
      for (int r = 0; r < 4; ++r) {
        int p = __shfl((int)mybf[r], lane ^ 1, 64);
        if (!(lane & 1)) {
          unsigned w = (unsigned)mybf[r] | ((unsigned)p << 16);
          *(unsigned*)(yb + (size_t)r * HID) = w;
        }
      }
    }
  }
}

// ---------------------------------------------------------------------------
extern "C" void kernel_launch(void* const* d_in, const int* in_sizes, int n_in,
                              void* d_out, int out_size, void* d_ws, size_t ws_size,
                              hipStream_t stream)
{
  (void)in_sizes; (void)n_in; (void)out_size; (void)ws_size;
  const float* x    = (const float*)d_in[0];
  const float* Wxz0 = (const float*)d_in[1];
  const float* gz0  = (const float*)d_in[3];
  const float* bz0  = (const float*)d_in[4];
  const float* Whz0 = (const float*)d_in[5];
  const float* bhz0 = (const float*)d_in[6];
  const float* Wxh0 = (const float*)d_in[7];
  const float* gh0  = (const float*)d_in[9];
  const float* bh0  = (const float*)d_in[10];
  const float* Whh0 = (const float*)d_in[11];
  const float* bhh0 = (const float*)d_in[12];
  const float* Wxz1 = (const float*)d_in[13];
  const float* gz1  = (const float*)d_in[15];
  const float* bz1  = (const float*)d_in[16];
  const float* Whz1 = (const float*)d_in[17];
  const float* bhz1 = (const float*)d_in[18];
  const float* Wxh1 = (const float*)d_in[19];
  const float* gh1  = (const float*)d_in[21];
  const float* bh1  = (const float*)d_in[22];
  const float* Whh1 = (const float*)d_in[23];
  const float* bhh1 = (const float*)d_in[24];

  char* ws = (char*)d_ws;
  // layout (total ~223 MB, < R3's proven 262.6 MB):
  //   flags0 @0 (16KB), flags1 @32768 (16KB)       [memset 64KB]
  //   hbuf   @65536  (256 KB)
  //   A      @524288 (131.072 MB)
  //   ys0bf  @131596288 (65.536 MB)   layer-0 ys, bf16
  //   Xbf    @197132288 (32.768 MB)   layer-0 input, bf16
  //   Wzbf   @229900288 (2 MB max)
  //   Whbf   @231997440 (2 MB max)
  unsigned* flags0 = (unsigned*)(ws);
  unsigned* flags1 = (unsigned*)(ws + 32768);
  unsigned short* hbuf  = (unsigned short*)(ws + 65536);
  unsigned short* A     = (unsigned short*)(ws + 524288);
  unsigned short* ys0bf = (unsigned short*)(ws + 131596288);
  unsigned short* Xbf   = (unsigned short*)(ws + 197132288);
  unsigned short* Wzbf  = (unsigned short*)(ws + 229900288);
  unsigned short* Whbf  = (unsigned short*)(ws + 231997440);
  float* out = (float*)d_out;

  hipMemsetAsync(ws, 0, 65536, stream);

  // ---- layer 0: converts ----
  conv_f32_bf16<<<dim3(8000), dim3(256), 0, stream>>>(x, Xbf);       // 16.384M elems
  conv_f32_bf16<<<dim3(256),  dim3(256), 0, stream>>>(Wxz0, Wzbf);   // 524288 elems
  conv_f32_bf16<<<dim3(256),  dim3(256), 0, stream>>>(Wxh0, Whbf);

  // ---- layer 0 ----
  proj_bn_kernel<<<dim3(8000), dim3(256), 0, stream>>>(
      Xbf, 512, Wzbf, Whbf, gz0, bz0, gh0, bh0, A);
  {
    const unsigned short* a0 = A;
    const float* whz = Whz0; const float* vbz = bhz0;
    const float* whh = Whh0; const float* vbh = bhh0;
    unsigned short* hb = hbuf; float* yy = (float*)ys0bf; unsigned* ff = flags0;
    int fmt = 0;
    void* kargs[9] = {&a0, &whz, &vbz, &whh, &vbh, &hb, &yy, &ff, &fmt};
    hipLaunchCooperativeKernel((const void*)scan_kernel, dim3(256), dim3(64),
                               kargs, 65536, stream);
  }

  // ---- layer 1: converts ----
  conv_f32_bf16<<<dim3(512), dim3(256), 0, stream>>>(Wxz1, Wzbf);    // 1.048M elems
  conv_f32_bf16<<<dim3(512), dim3(256), 0, stream>>>(Wxh1, Whbf);

  // ---- layer 1 ----
  proj_bn_kernel<<<dim3(8000), dim3(256), 0, stream>>>(
      ys0bf, 1024, Wzbf, Whbf, gz1, bz1, gh1, bh1, A);
  {
    const unsigned short* a0 = A;
    const float* whz = Whz1; const float* vbz = bhz1;
    const float* whh = Whh1; const float* vbh = bhh1;
    unsigned short* hb = hbuf; float* yy = out; unsigned* ff = flags1;
    int fmt = 1;
    void* kargs[9] = {&a0, &whz, &vbz, &whh, &vbh, &hb, &yy, &ff, &fmt};
    hipLaunchCooperativeKernel((const void*)scan_kernel, dim3(256), dim3(64),
                               kargs, 65536, stream);
  }
}